// Round 10
// baseline (144.113 us; speedup 1.0000x reference)
//
#include <hip/hip_runtime.h>
#include <hip/hip_bf16.h>

// B=2, T=2048, C=768, H=12, D=64. 3C=2304. BT=4096.
// prologue (cast + weight transposes); QKV GEMM 128x96 BK=64 reg-prefetch (d1);
// causal flash attention: S^T form, 128-key x 128-q blocks (32 q/wave) to halve
// LDS traffic per unit work, packed P stores, fixed-max softmax, rank-paired;
// proj GEMM 64x96 BK=64 reg-prefetch -> fp32 out.

using half4   = __attribute__((ext_vector_type(4))) _Float16;
using half8   = __attribute__((ext_vector_type(8))) _Float16;
using floatx4 = __attribute__((ext_vector_type(4))) float;

#define T_SEQ 2048
#define NHEAD 12
#define HDIM 64
#define C3 2304
#define CDIM 768
#define BT 4096
#define BH 24

static __device__ inline _Float16 f2h(float f) { return (_Float16)f; }

// ---------------- fused prologue: weight transposes + x cast ----------------
__global__ __launch_bounds__(256)
void prologue(const float* __restrict__ x, const float* __restrict__ wa,
              const float* __restrict__ wp, _Float16* __restrict__ xb,
              _Float16* __restrict__ wTa, _Float16* __restrict__ wTp) {
    __shared__ float tile[32][33];
    int blk = blockIdx.x, tid = threadIdx.x;
    if (blk < 2304) {
        const float* w; _Float16* wT; int K, N, bx, by;
        if (blk < 1728) { w = wa; wT = wTa; K = CDIM; N = C3; bx = blk % 72; by = blk / 72; }
        else { int b2 = blk - 1728; w = wp; wT = wTp; K = CDIM; N = CDIM; bx = b2 % 24; by = b2 / 24; }
        int tx = tid & 31, ty = tid >> 5;
        #pragma unroll
        for (int j = 0; j < 32; j += 8) {
            int k = by * 32 + ty + j, n = bx * 32 + tx;
            tile[ty + j][tx] = w[(long)k * N + n];
        }
        __syncthreads();
        #pragma unroll
        for (int j = 0; j < 32; j += 8) {
            int nO = bx * 32 + ty + j, kO = by * 32 + tx;
            wT[(long)nO * K + kO] = f2h(tile[tx][ty + j]);
        }
    } else {
        int b2 = blk - 2304;                 // 768 blocks x 4096 elems
        long e0 = (long)b2 * 4096 + tid * 16;
        floatx4 f0 = *(const floatx4*)&x[e0];
        floatx4 f1 = *(const floatx4*)&x[e0 + 4];
        floatx4 f2 = *(const floatx4*)&x[e0 + 8];
        floatx4 f3 = *(const floatx4*)&x[e0 + 12];
        half8 h0, h1;
        #pragma unroll
        for (int j = 0; j < 4; ++j) {
            h0[j] = f2h(f0[j]); h0[4 + j] = f2h(f1[j]);
            h1[j] = f2h(f2[j]); h1[4 + j] = f2h(f3[j]);
        }
        *(half8*)&xb[e0] = h0;
        *(half8*)&xb[e0 + 8] = h1;
    }
}

// ---------------- QKV GEMM: 128x96 tile, BK=64, register-prefetch (round 8) --
__global__ __launch_bounds__(256)
void gemm_qkv(const _Float16* __restrict__ A, const _Float16* __restrict__ Bt,
              const float* __restrict__ bias,
              _Float16* __restrict__ Qb, _Float16* __restrict__ Kb,
              _Float16* __restrict__ Vt) {
    __shared__ __align__(16) _Float16 As[128 * 72];
    __shared__ __align__(16) _Float16 Bs[96 * 72];
    const int K = CDIM;
    int tid = threadIdx.x;
    int m0 = blockIdx.x * 128, n0 = blockIdx.y * 96;
    int w = tid >> 6, l = tid & 63;
    int wm = (w >> 1) * 64, wn = (w & 1) * 48;
    int lr = l & 15, lq = l >> 4;

    int rs = tid >> 3, cs = (tid & 7) * 8;

    floatx4 acc[4][3] = {};

    half8 Ar[4], Br[3];
    #pragma unroll
    for (int j = 0; j < 4; ++j)
        Ar[j] = *(const half8*)&A[(long)(m0 + j * 32 + rs) * K + cs];
    #pragma unroll
    for (int j = 0; j < 3; ++j)
        Br[j] = *(const half8*)&Bt[(long)(n0 + j * 32 + rs) * K + cs];

    for (int kb = 0; kb < K; kb += 64) {
        #pragma unroll
        for (int j = 0; j < 4; ++j)
            *(half8*)&As[(j * 32 + rs) * 72 + cs] = Ar[j];
        #pragma unroll
        for (int j = 0; j < 3; ++j)
            *(half8*)&Bs[(j * 32 + rs) * 72 + cs] = Br[j];
        __syncthreads();
        if (kb + 64 < K) {
            #pragma unroll
            for (int j = 0; j < 4; ++j)
                Ar[j] = *(const half8*)&A[(long)(m0 + j * 32 + rs) * K + kb + 64 + cs];
            #pragma unroll
            for (int j = 0; j < 3; ++j)
                Br[j] = *(const half8*)&Bt[(long)(n0 + j * 32 + rs) * K + kb + 64 + cs];
        }
        #pragma unroll
        for (int kh = 0; kh < 2; ++kh) {
            half8 af[4], bf[3];
            #pragma unroll
            for (int i = 0; i < 4; ++i)
                af[i] = *(const half8*)&As[(wm + i * 16 + lr) * 72 + kh * 32 + lq * 8];
            #pragma unroll
            for (int i = 0; i < 3; ++i)
                bf[i] = *(const half8*)&Bs[(wn + i * 16 + lr) * 72 + kh * 32 + lq * 8];
            #pragma unroll
            for (int mi = 0; mi < 4; ++mi)
                #pragma unroll
                for (int ni = 0; ni < 3; ++ni)
                    acc[mi][ni] = __builtin_amdgcn_mfma_f32_16x16x32_f16(af[mi], bf[ni], acc[mi][ni], 0, 0, 0);
        }
        __syncthreads();
    }

    int region = n0 / CDIM;
    if (region < 2) {
        _Float16* O = region ? Kb : Qb;
        int nc0 = n0 - region * CDIM + wn;
        #pragma unroll
        for (int mi = 0; mi < 4; ++mi)
            #pragma unroll
            for (int ni = 0; ni < 3; ++ni) {
                int col = nc0 + ni * 16 + lr;
                float bsc = bias[region * CDIM + col];
                #pragma unroll
                for (int r = 0; r < 4; ++r) {
                    int row = m0 + wm + mi * 16 + lq * 4 + r;
                    O[(long)row * CDIM + col] = f2h(acc[mi][ni][r] + bsc);
                }
            }
    } else {
        #pragma unroll
        for (int mi = 0; mi < 4; ++mi)
            #pragma unroll
            for (int ni = 0; ni < 3; ++ni) {
                int cv = n0 - 2 * CDIM + wn + ni * 16 + lr;    // 0..767
                float bsc = bias[2 * CDIM + cv];
                int h = cv >> 6, d = cv & 63;
                int t0 = m0 + wm + mi * 16 + lq * 4;
                int bb = t0 >> 11, t = t0 & 2047;
                half4 hv;
                #pragma unroll
                for (int r = 0; r < 4; ++r) hv[r] = f2h(acc[mi][ni][r] + bsc);
                *(half4*)&Vt[(((long)bb * NHEAD + h) * HDIM + d) * T_SEQ + t] = hv;
            }
    }
}

// ---------------- proj GEMM: 64x96 tile, BK=64, reg-prefetch (round 8) -------
__global__ __launch_bounds__(256)
void gemm_proj(const _Float16* __restrict__ A, const _Float16* __restrict__ Bt,
               const float* __restrict__ bias, float* __restrict__ Cout) {
    __shared__ __align__(16) _Float16 As[64 * 72];
    __shared__ __align__(16) _Float16 Bs[96 * 72];
    const int K = CDIM, N = CDIM;
    int tid = threadIdx.x;
    int m0 = blockIdx.x * 64, n0 = blockIdx.y * 96;
    int w = tid >> 6, l = tid & 63;
    int wm = (w >> 1) * 32, wn = (w & 1) * 48;
    int lr = l & 15, lq = l >> 4;

    int rs = tid >> 3, cs = (tid & 7) * 8;

    floatx4 acc[2][3] = {};

    half8 Ar[2], Br[3];
    #pragma unroll
    for (int j = 0; j < 2; ++j)
        Ar[j] = *(const half8*)&A[(long)(m0 + j * 32 + rs) * K + cs];
    #pragma unroll
    for (int j = 0; j < 3; ++j)
        Br[j] = *(const half8*)&Bt[(long)(n0 + j * 32 + rs) * K + cs];

    for (int kb = 0; kb < K; kb += 64) {
        #pragma unroll
        for (int j = 0; j < 2; ++j)
            *(half8*)&As[(j * 32 + rs) * 72 + cs] = Ar[j];
        #pragma unroll
        for (int j = 0; j < 3; ++j)
            *(half8*)&Bs[(j * 32 + rs) * 72 + cs] = Br[j];
        __syncthreads();
        if (kb + 64 < K) {
            #pragma unroll
            for (int j = 0; j < 2; ++j)
                Ar[j] = *(const half8*)&A[(long)(m0 + j * 32 + rs) * K + kb + 64 + cs];
            #pragma unroll
            for (int j = 0; j < 3; ++j)
                Br[j] = *(const half8*)&Bt[(long)(n0 + j * 32 + rs) * K + kb + 64 + cs];
        }
        #pragma unroll
        for (int kh = 0; kh < 2; ++kh) {
            half8 af[2], bf[3];
            #pragma unroll
            for (int i = 0; i < 2; ++i)
                af[i] = *(const half8*)&As[(wm + i * 16 + lr) * 72 + kh * 32 + lq * 8];
            #pragma unroll
            for (int i = 0; i < 3; ++i)
                bf[i] = *(const half8*)&Bs[(wn + i * 16 + lr) * 72 + kh * 32 + lq * 8];
            #pragma unroll
            for (int mi = 0; mi < 2; ++mi)
                #pragma unroll
                for (int ni = 0; ni < 3; ++ni)
                    acc[mi][ni] = __builtin_amdgcn_mfma_f32_16x16x32_f16(af[mi], bf[ni], acc[mi][ni], 0, 0, 0);
        }
        __syncthreads();
    }
    #pragma unroll
    for (int mi = 0; mi < 2; ++mi)
        #pragma unroll
        for (int ni = 0; ni < 3; ++ni) {
            int col = n0 + wn + ni * 16 + lr;
            float b = bias[col];
            #pragma unroll
            for (int r = 0; r < 4; ++r) {
                int row = m0 + wm + mi * 16 + lq * 4 + r;
                Cout[(long)row * N + col] = acc[mi][ni][r] + b;
            }
        }
}

// ---------------- causal flash attention: S^T form, 128q x 128k blocks -------
// Q,K: [b][t][h*64+d] f16. Vt: [b][h][d][t] f16. y: [b][t][h*64+d] f16.
// Block = 4 waves x 32 q = 128 q rows; 128-key LDS tiles. Each bk/bv LDS read
// feeds 2 MFMAs (two q-groups) -> ~0.58x LDS traffic per unit work vs 16 q/wave.
// Grid 384 (T/128=16 q-tiles x 24 bh), rank order r = i<256 ? i : 639-i pairs
// heavy ranks with light ranks under round-robin block->CU assignment.
__global__ __launch_bounds__(256)
void attn_kernel(const _Float16* __restrict__ Qb, const _Float16* __restrict__ Kb,
                 const _Float16* __restrict__ Vt, _Float16* __restrict__ y) {
    __shared__ __align__(16) _Float16 Ks[128 * 72];     // [key][d]
    __shared__ __align__(16) _Float16 Vs[64 * 136];     // [d][key]
    __shared__ __align__(16) _Float16 Ps[4][32 * 136];  // per-wave [q][key]
    int tid = threadIdx.x;
    int w = tid >> 6, l = tid & 63;
    int lr = l & 15, lq = l >> 4;
    int i = blockIdx.x;
    int r_ = (i < 256) ? i : 639 - i;      // ranks 0..255, then 383..256
    int qt = 15 - r_ / 24;                 // q-tile (heavy first)
    int bh = r_ % 24;
    int b = bh / NHEAD, h = bh % NHEAD;
    int q0 = qt * 128 + w * 32;

    const _Float16* Qp = Qb + (long)b * T_SEQ * CDIM + h * HDIM;
    const _Float16* Kg = Kb + (long)b * T_SEQ * CDIM + h * HDIM;
    const _Float16* Vg = Vt + (long)bh * HDIM * T_SEQ;

    int kr = tid >> 3, kc = (tid & 7) * 8;     // K staging: rows +j*32
    int vr = tid >> 4, vc = (tid & 15) * 8;    // V staging: rows +j*16

    const float qscale = 0.125f * 1.44269504f;
    half8 aq[2][2];                            // [q-group][kh]
    #pragma unroll
    for (int qg = 0; qg < 2; ++qg)
        #pragma unroll
        for (int kh = 0; kh < 2; ++kh) {
            half8 v = *(const half8*)&Qp[(long)(q0 + qg * 16 + lr) * CDIM + kh * 32 + lq * 8];
            #pragma unroll
            for (int j = 0; j < 8; ++j) v[j] = f2h((float)v[j] * qscale);
            aq[qg][kh] = v;
        }

    int nk = qt + 1;                           // 128-key tiles covering [0,(qt+1)*128)

    half8 Kr[4], Vr[4];
    #pragma unroll
    for (int j = 0; j < 4; ++j) {
        Kr[j] = *(const half8*)&Kg[(long)(j * 32 + kr) * CDIM + kc];
        Vr[j] = *(const half8*)&Vg[(long)(j * 16 + vr) * T_SEQ + vc];
    }

    float psum[2] = {0.f, 0.f};
    floatx4 acc[2][4] = {};

    for (int kt = 0; kt < nk; ++kt) {
        int kbase = kt * 128;
        #pragma unroll
        for (int j = 0; j < 4; ++j) {
            *(half8*)&Ks[(j * 32 + kr) * 72 + kc] = Kr[j];
            *(half8*)&Vs[(j * 16 + vr) * 136 + vc] = Vr[j];
        }
        __syncthreads();
        if (kt + 1 < nk) {
            int nb = kbase + 128;
            #pragma unroll
            for (int j = 0; j < 4; ++j) {
                Kr[j] = *(const half8*)&Kg[(long)(nb + j * 32 + kr) * CDIM + kc];
                Vr[j] = *(const half8*)&Vg[(long)(j * 16 + vr) * T_SEQ + nb + vc];
            }
        }

        // S^T = K Q^T for both q-groups; each bk read feeds 2 MFMAs
        floatx4 sacc[2][8];
        #pragma unroll
        for (int qg = 0; qg < 2; ++qg)
            #pragma unroll
            for (int s = 0; s < 8; ++s) sacc[qg][s] = floatx4{0.f, 0.f, 0.f, 0.f};
        #pragma unroll
        for (int s = 0; s < 8; ++s)
            #pragma unroll
            for (int kh = 0; kh < 2; ++kh) {
                half8 bk = *(const half8*)&Ks[(s * 16 + lr) * 72 + kh * 32 + lq * 8];
                sacc[0][s] = __builtin_amdgcn_mfma_f32_16x16x32_f16(bk, aq[0][kh], sacc[0][s], 0, 0, 0);
                sacc[1][s] = __builtin_amdgcn_mfma_f32_16x16x32_f16(bk, aq[1][kh], sacc[1][s], 0, 0, 0);
            }

        if (kt == nk - 1) {    // diagonal tile: causal mask
            #pragma unroll
            for (int qg = 0; qg < 2; ++qg) {
                int qrow = q0 + qg * 16 + lr;
                #pragma unroll
                for (int s = 0; s < 8; ++s) {
                    half4 hv;
                    #pragma unroll
                    for (int r = 0; r < 4; ++r) {
                        int key = kbase + s * 16 + lq * 4 + r;
                        float p = (key > qrow) ? 0.f : __builtin_amdgcn_exp2f(sacc[qg][s][r]);
                        psum[qg] += p;
                        hv[r] = f2h(p);
                    }
                    *(half4*)&Ps[w][(qg * 16 + lr) * 136 + s * 16 + lq * 4] = hv;
                }
            }
        } else {
            #pragma unroll
            for (int qg = 0; qg < 2; ++qg)
                #pragma unroll
                for (int s = 0; s < 8; ++s) {
                    half4 hv;
                    #pragma unroll
                    for (int r = 0; r < 4; ++r) {
                        float p = __builtin_amdgcn_exp2f(sacc[qg][s][r]);
                        psum[qg] += p;
                        hv[r] = f2h(p);
                    }
                    *(half4*)&Ps[w][(qg * 16 + lr) * 136 + s * 16 + lq * 4] = hv;
                }
        }

        half8 ap[2][4];
        #pragma unroll
        for (int qg = 0; qg < 2; ++qg)
            #pragma unroll
            for (int kk = 0; kk < 4; ++kk)
                ap[qg][kk] = *(const half8*)&Ps[w][(qg * 16 + lr) * 136 + kk * 32 + lq * 8];
        #pragma unroll
        for (int n = 0; n < 4; ++n)
            #pragma unroll
            for (int kk = 0; kk < 4; ++kk) {
                half8 bv = *(const half8*)&Vs[(n * 16 + lr) * 136 + kk * 32 + lq * 8];
                acc[0][n] = __builtin_amdgcn_mfma_f32_16x16x32_f16(ap[0][kk], bv, acc[0][n], 0, 0, 0);
                acc[1][n] = __builtin_amdgcn_mfma_f32_16x16x32_f16(ap[1][kk], bv, acc[1][n], 0, 0, 0);
            }
        __syncthreads();
    }

    // reduce psum across the 4 quads (lanes lr, lr+16, lr+32, lr+48 share q)
    #pragma unroll
    for (int qg = 0; qg < 2; ++qg) {
        float L = psum[qg];
        L += __shfl_xor(L, 16, 64);
        L += __shfl_xor(L, 32, 64);
        float Lr[4];
        #pragma unroll
        for (int r = 0; r < 4; ++r) Lr[r] = __shfl(L, lq * 4 + r, 64);
        #pragma unroll
        for (int n = 0; n < 4; ++n)
            #pragma unroll
            for (int r = 0; r < 4; ++r) {
                int row = q0 + qg * 16 + lq * 4 + r;
                float v = acc[qg][n][r] / Lr[r];
                y[((long)(b * T_SEQ) + row) * CDIM + h * HDIM + n * 16 + lr] = f2h(v);
            }
    }
}

extern "C" void kernel_launch(void* const* d_in, const int* in_sizes, int n_in,
                              void* d_out, int out_size, void* d_ws, size_t ws_size,
                              hipStream_t stream) {
    const float* x      = (const float*)d_in[0];
    const float* w_attn = (const float*)d_in[1];
    const float* b_attn = (const float*)d_in[2];
    const float* w_proj = (const float*)d_in[3];
    const float* b_proj = (const float*)d_in[4];
    float* out = (float*)d_out;

    char* ws = (char*)d_ws;
    _Float16* xb  = (_Float16*)(ws);                // 6,291,456
    _Float16* wTa = (_Float16*)(ws + 6291456);      // 3,538,944
    _Float16* wTp = (_Float16*)(ws + 9830400);      // 1,179,648
    _Float16* Qb  = (_Float16*)(ws + 11010048);     // 6,291,456
    _Float16* Kb  = (_Float16*)(ws + 17301504);     // 6,291,456
    _Float16* Vt  = (_Float16*)(ws + 23592960);     // 6,291,456
    _Float16* yb  = (_Float16*)(ws + 29884416);     // 6,291,456

    prologue<<<3072, 256, 0, stream>>>(x, w_attn, w_proj, xb, wTa, wTp);

    gemm_qkv<<<dim3(BT / 128, C3 / 96), 256, 0, stream>>>(xb, wTa, b_attn, Qb, Kb, Vt);

    attn_kernel<<<BH * (T_SEQ / 128), 256, 0, stream>>>(Qb, Kb, Vt, yb);

    gemm_proj<<<dim3(BT / 64, CDIM / 96), 256, 0, stream>>>(yb, wTp, b_proj, out);
}

// Round 11
// 140.223 us; speedup vs baseline: 1.0277x; 1.0277x over previous
//
#include <hip/hip_runtime.h>
#include <hip/hip_bf16.h>

// B=2, T=2048, C=768, H=12, D=64. 3C=2304. BT=4096.
// Round-8 structure + XOR-swizzled unpadded LDS (zero excess bank conflicts):
// prologue (cast + weight transposes); QKV GEMM 128x96 BK=64 reg-prefetch;
// causal flash attention (S^T form, packed P, 128-key tiles, fixed-max softmax,
// rank-paired); proj GEMM 64x96 BK=64 -> fp32 out.

using half4   = __attribute__((ext_vector_type(4))) _Float16;
using half8   = __attribute__((ext_vector_type(8))) _Float16;
using floatx4 = __attribute__((ext_vector_type(4))) float;

#define T_SEQ 2048
#define NHEAD 12
#define HDIM 64
#define C3 2304
#define CDIM 768
#define BT 4096
#define BH 24

static __device__ inline _Float16 f2h(float f) { return (_Float16)f; }

// XOR-swizzled LDS addressing (halves). Row stride 64 (8 groups of 8 halves)
// or 128 (16 groups). Group index is XORed with low row bits so that b128
// accesses indexed by (row=lr, colgrp=f(lq)) spread across all bank groups.
static __device__ __forceinline__ int swz8(int row, int cg)  { return (row << 6) + ((cg ^ (row & 7))  << 3); }
static __device__ __forceinline__ int swz16(int row, int cg) { return (row << 7) + ((cg ^ (row & 15)) << 3); }

// ---------------- fused prologue: weight transposes + x cast ----------------
__global__ __launch_bounds__(256)
void prologue(const float* __restrict__ x, const float* __restrict__ wa,
              const float* __restrict__ wp, _Float16* __restrict__ xb,
              _Float16* __restrict__ wTa, _Float16* __restrict__ wTp) {
    __shared__ float tile[32][33];
    int blk = blockIdx.x, tid = threadIdx.x;
    if (blk < 2304) {
        const float* w; _Float16* wT; int K, N, bx, by;
        if (blk < 1728) { w = wa; wT = wTa; K = CDIM; N = C3; bx = blk % 72; by = blk / 72; }
        else { int b2 = blk - 1728; w = wp; wT = wTp; K = CDIM; N = CDIM; bx = b2 % 24; by = b2 / 24; }
        int tx = tid & 31, ty = tid >> 5;
        #pragma unroll
        for (int j = 0; j < 32; j += 8) {
            int k = by * 32 + ty + j, n = bx * 32 + tx;
            tile[ty + j][tx] = w[(long)k * N + n];
        }
        __syncthreads();
        #pragma unroll
        for (int j = 0; j < 32; j += 8) {
            int nO = bx * 32 + ty + j, kO = by * 32 + tx;
            wT[(long)nO * K + kO] = f2h(tile[tx][ty + j]);
        }
    } else {
        int b2 = blk - 2304;                 // 768 blocks x 4096 elems
        long e0 = (long)b2 * 4096 + tid * 16;
        floatx4 f0 = *(const floatx4*)&x[e0];
        floatx4 f1 = *(const floatx4*)&x[e0 + 4];
        floatx4 f2 = *(const floatx4*)&x[e0 + 8];
        floatx4 f3 = *(const floatx4*)&x[e0 + 12];
        half8 h0, h1;
        #pragma unroll
        for (int j = 0; j < 4; ++j) {
            h0[j] = f2h(f0[j]); h0[4 + j] = f2h(f1[j]);
            h1[j] = f2h(f2[j]); h1[4 + j] = f2h(f3[j]);
        }
        *(half8*)&xb[e0] = h0;
        *(half8*)&xb[e0 + 8] = h1;
    }
}

// ---------------- QKV GEMM: 128x96 tile, BK=64, reg-prefetch, swizzled LDS ---
__global__ __launch_bounds__(256)
void gemm_qkv(const _Float16* __restrict__ A, const _Float16* __restrict__ Bt,
              const float* __restrict__ bias,
              _Float16* __restrict__ Qb, _Float16* __restrict__ Kb,
              _Float16* __restrict__ Vt) {
    __shared__ __align__(16) _Float16 As[128 * 64];
    __shared__ __align__(16) _Float16 Bs[96 * 64];
    const int K = CDIM;
    int tid = threadIdx.x;
    int m0 = blockIdx.x * 128, n0 = blockIdx.y * 96;
    int w = tid >> 6, l = tid & 63;
    int wm = (w >> 1) * 64, wn = (w & 1) * 48;
    int lr = l & 15, lq = l >> 4;

    int rs = tid >> 3, cs = (tid & 7) * 8, cg = tid & 7;

    floatx4 acc[4][3] = {};

    half8 Ar[4], Br[3];
    #pragma unroll
    for (int j = 0; j < 4; ++j)
        Ar[j] = *(const half8*)&A[(long)(m0 + j * 32 + rs) * K + cs];
    #pragma unroll
    for (int j = 0; j < 3; ++j)
        Br[j] = *(const half8*)&Bt[(long)(n0 + j * 32 + rs) * K + cs];

    for (int kb = 0; kb < K; kb += 64) {
        #pragma unroll
        for (int j = 0; j < 4; ++j)
            *(half8*)&As[swz8(j * 32 + rs, cg)] = Ar[j];
        #pragma unroll
        for (int j = 0; j < 3; ++j)
            *(half8*)&Bs[swz8(j * 32 + rs, cg)] = Br[j];
        __syncthreads();
        if (kb + 64 < K) {
            #pragma unroll
            for (int j = 0; j < 4; ++j)
                Ar[j] = *(const half8*)&A[(long)(m0 + j * 32 + rs) * K + kb + 64 + cs];
            #pragma unroll
            for (int j = 0; j < 3; ++j)
                Br[j] = *(const half8*)&Bt[(long)(n0 + j * 32 + rs) * K + kb + 64 + cs];
        }
        #pragma unroll
        for (int kh = 0; kh < 2; ++kh) {
            half8 af[4], bf[3];
            #pragma unroll
            for (int i = 0; i < 4; ++i)
                af[i] = *(const half8*)&As[swz8(wm + i * 16 + lr, kh * 4 + lq)];
            #pragma unroll
            for (int i = 0; i < 3; ++i)
                bf[i] = *(const half8*)&Bs[swz8(wn + i * 16 + lr, kh * 4 + lq)];
            #pragma unroll
            for (int mi = 0; mi < 4; ++mi)
                #pragma unroll
                for (int ni = 0; ni < 3; ++ni)
                    acc[mi][ni] = __builtin_amdgcn_mfma_f32_16x16x32_f16(af[mi], bf[ni], acc[mi][ni], 0, 0, 0);
        }
        __syncthreads();
    }

    int region = n0 / CDIM;
    if (region < 2) {
        _Float16* O = region ? Kb : Qb;
        int nc0 = n0 - region * CDIM + wn;
        #pragma unroll
        for (int mi = 0; mi < 4; ++mi)
            #pragma unroll
            for (int ni = 0; ni < 3; ++ni) {
                int col = nc0 + ni * 16 + lr;
                float bsc = bias[region * CDIM + col];
                #pragma unroll
                for (int r = 0; r < 4; ++r) {
                    int row = m0 + wm + mi * 16 + lq * 4 + r;
                    O[(long)row * CDIM + col] = f2h(acc[mi][ni][r] + bsc);
                }
            }
    } else {
        #pragma unroll
        for (int mi = 0; mi < 4; ++mi)
            #pragma unroll
            for (int ni = 0; ni < 3; ++ni) {
                int cv = n0 - 2 * CDIM + wn + ni * 16 + lr;    // 0..767
                float bsc = bias[2 * CDIM + cv];
                int h = cv >> 6, d = cv & 63;
                int t0 = m0 + wm + mi * 16 + lq * 4;
                int bb = t0 >> 11, t = t0 & 2047;
                half4 hv;
                #pragma unroll
                for (int r = 0; r < 4; ++r) hv[r] = f2h(acc[mi][ni][r] + bsc);
                *(half4*)&Vt[(((long)bb * NHEAD + h) * HDIM + d) * T_SEQ + t] = hv;
            }
    }
}

// ---------------- proj GEMM: 64x96 tile, BK=64, reg-prefetch, swizzled LDS ---
__global__ __launch_bounds__(256)
void gemm_proj(const _Float16* __restrict__ A, const _Float16* __restrict__ Bt,
               const float* __restrict__ bias, float* __restrict__ Cout) {
    __shared__ __align__(16) _Float16 As[64 * 64];
    __shared__ __align__(16) _Float16 Bs[96 * 64];
    const int K = CDIM, N = CDIM;
    int tid = threadIdx.x;
    int m0 = blockIdx.x * 64, n0 = blockIdx.y * 96;
    int w = tid >> 6, l = tid & 63;
    int wm = (w >> 1) * 32, wn = (w & 1) * 48;
    int lr = l & 15, lq = l >> 4;

    int rs = tid >> 3, cs = (tid & 7) * 8, cg = tid & 7;

    floatx4 acc[2][3] = {};

    half8 Ar[2], Br[3];
    #pragma unroll
    for (int j = 0; j < 2; ++j)
        Ar[j] = *(const half8*)&A[(long)(m0 + j * 32 + rs) * K + cs];
    #pragma unroll
    for (int j = 0; j < 3; ++j)
        Br[j] = *(const half8*)&Bt[(long)(n0 + j * 32 + rs) * K + cs];

    for (int kb = 0; kb < K; kb += 64) {
        #pragma unroll
        for (int j = 0; j < 2; ++j)
            *(half8*)&As[swz8(j * 32 + rs, cg)] = Ar[j];
        #pragma unroll
        for (int j = 0; j < 3; ++j)
            *(half8*)&Bs[swz8(j * 32 + rs, cg)] = Br[j];
        __syncthreads();
        if (kb + 64 < K) {
            #pragma unroll
            for (int j = 0; j < 2; ++j)
                Ar[j] = *(const half8*)&A[(long)(m0 + j * 32 + rs) * K + kb + 64 + cs];
            #pragma unroll
            for (int j = 0; j < 3; ++j)
                Br[j] = *(const half8*)&Bt[(long)(n0 + j * 32 + rs) * K + kb + 64 + cs];
        }
        #pragma unroll
        for (int kh = 0; kh < 2; ++kh) {
            half8 af[2], bf[3];
            #pragma unroll
            for (int i = 0; i < 2; ++i)
                af[i] = *(const half8*)&As[swz8(wm + i * 16 + lr, kh * 4 + lq)];
            #pragma unroll
            for (int i = 0; i < 3; ++i)
                bf[i] = *(const half8*)&Bs[swz8(wn + i * 16 + lr, kh * 4 + lq)];
            #pragma unroll
            for (int mi = 0; mi < 2; ++mi)
                #pragma unroll
                for (int ni = 0; ni < 3; ++ni)
                    acc[mi][ni] = __builtin_amdgcn_mfma_f32_16x16x32_f16(af[mi], bf[ni], acc[mi][ni], 0, 0, 0);
        }
        __syncthreads();
    }
    #pragma unroll
    for (int mi = 0; mi < 2; ++mi)
        #pragma unroll
        for (int ni = 0; ni < 3; ++ni) {
            int col = n0 + wn + ni * 16 + lr;
            float b = bias[col];
            #pragma unroll
            for (int r = 0; r < 4; ++r) {
                int row = m0 + wm + mi * 16 + lq * 4 + r;
                Cout[(long)row * N + col] = acc[mi][ni][r] + b;
            }
        }
}

// ---------------- causal flash attention: S^T form, swizzled LDS -------------
// Q,K: [b][t][h*64+d] f16. Vt: [b][h][d][t] f16. y: [b][t][h*64+d] f16.
// Block = 4 waves x 16 q = 64 q rows; 128-key LDS tiles; fixed-max softmax.
// Ks [128][64] swz8; Vs [64][128] swz16; Ps [16][128] swz16 per wave.
__global__ __launch_bounds__(256)
void attn_kernel(const _Float16* __restrict__ Qb, const _Float16* __restrict__ Kb,
                 const _Float16* __restrict__ Vt, _Float16* __restrict__ y) {
    __shared__ __align__(16) _Float16 Ks[128 * 64];
    __shared__ __align__(16) _Float16 Vs[64 * 128];
    __shared__ __align__(16) _Float16 Ps[4][16 * 128];
    int tid = threadIdx.x;
    int w = tid >> 6, l = tid & 63;
    int lr = l & 15, lq = l >> 4;
    int i = blockIdx.x;
    int round = i >> 8, c = i & 255;
    int r_ = (round == 0) ? c : (round == 1 ? 767 - c : 256 + c);
    int qb = 31 - r_ / 24;
    int bh = r_ % 24;
    int b = bh / NHEAD, h = bh % NHEAD;
    int q0 = qb * 64 + w * 16;

    const _Float16* Qp = Qb + (long)b * T_SEQ * CDIM + h * HDIM;
    const _Float16* Kg = Kb + (long)b * T_SEQ * CDIM + h * HDIM;
    const _Float16* Vg = Vt + (long)bh * HDIM * T_SEQ;

    int kr = tid >> 3, kc = (tid & 7) * 8, kcg = tid & 7;   // K staging
    int vr = tid >> 4, vc = (tid & 15) * 8, vcg = tid & 15; // V staging

    const float qscale = 0.125f * 1.44269504f;
    half8 aq[2];
    #pragma unroll
    for (int kk = 0; kk < 2; ++kk) {
        aq[kk] = *(const half8*)&Qp[(long)(q0 + lr) * CDIM + kk * 32 + lq * 8];
        #pragma unroll
        for (int j = 0; j < 8; ++j) aq[kk][j] = f2h((float)aq[kk][j] * qscale);
    }

    int nk = (qb + 2) >> 1;   // 128-key tiles covering [0, qb*64+64)

    half8 Kr[4], Vr[4];
    #pragma unroll
    for (int j = 0; j < 4; ++j) {
        Kr[j] = *(const half8*)&Kg[(long)(j * 32 + kr) * CDIM + kc];
        Vr[j] = *(const half8*)&Vg[(long)(j * 16 + vr) * T_SEQ + vc];
    }

    float psum = 0.f;
    floatx4 acc[4] = {};
    int qrow = q0 + lr;

    for (int kt = 0; kt < nk; ++kt) {
        int kbase = kt * 128;
        #pragma unroll
        for (int j = 0; j < 4; ++j) {
            *(half8*)&Ks[swz8(j * 32 + kr, kcg)] = Kr[j];
            *(half8*)&Vs[swz16(j * 16 + vr, vcg)] = Vr[j];
        }
        __syncthreads();
        if (kt + 1 < nk) {
            int nb = kbase + 128;
            #pragma unroll
            for (int j = 0; j < 4; ++j) {
                Kr[j] = *(const half8*)&Kg[(long)(nb + j * 32 + kr) * CDIM + kc];
                Vr[j] = *(const half8*)&Vg[(long)(j * 16 + vr) * T_SEQ + nb + vc];
            }
        }

        // S^T = K Q^T : C rows = keys, cols = q
        floatx4 sacc[8];
        #pragma unroll
        for (int s = 0; s < 8; ++s) sacc[s] = floatx4{0.f, 0.f, 0.f, 0.f};
        #pragma unroll
        for (int s = 0; s < 8; ++s)
            #pragma unroll
            for (int kh = 0; kh < 2; ++kh) {
                half8 bk = *(const half8*)&Ks[swz8(s * 16 + lr, kh * 4 + lq)];
                sacc[s] = __builtin_amdgcn_mfma_f32_16x16x32_f16(bk, aq[kh], sacc[s], 0, 0, 0);
            }

        if (kt == nk - 1) {   // tile containing the diagonal
            #pragma unroll
            for (int s = 0; s < 8; ++s) {
                half4 hv;
                #pragma unroll
                for (int r = 0; r < 4; ++r) {
                    int key = kbase + s * 16 + lq * 4 + r;
                    float p = (key > qrow) ? 0.f : __builtin_amdgcn_exp2f(sacc[s][r]);
                    psum += p;
                    hv[r] = f2h(p);
                }
                *(half4*)&Ps[w][swz16(lr, s * 2 + (lq >> 1)) + (lq & 1) * 4] = hv;
            }
        } else {
            #pragma unroll
            for (int s = 0; s < 8; ++s) {
                half4 hv;
                #pragma unroll
                for (int r = 0; r < 4; ++r) {
                    float p = __builtin_amdgcn_exp2f(sacc[s][r]);
                    psum += p;
                    hv[r] = f2h(p);
                }
                *(half4*)&Ps[w][swz16(lr, s * 2 + (lq >> 1)) + (lq & 1) * 4] = hv;
            }
        }

        half8 ap[4];
        #pragma unroll
        for (int kk = 0; kk < 4; ++kk)
            ap[kk] = *(const half8*)&Ps[w][swz16(lr, kk * 4 + lq)];
        #pragma unroll
        for (int n = 0; n < 4; ++n) {
            #pragma unroll
            for (int kk = 0; kk < 4; ++kk) {
                half8 bv = *(const half8*)&Vs[swz16(n * 16 + lr, kk * 4 + lq)];
                acc[n] = __builtin_amdgcn_mfma_f32_16x16x32_f16(ap[kk], bv, acc[n], 0, 0, 0);
            }
        }
        __syncthreads();
    }

    // reduce psum over the 4 quads holding the same q
    float L = psum;
    L += __shfl_xor(L, 16, 64);
    L += __shfl_xor(L, 32, 64);
    float Lr[4];
    #pragma unroll
    for (int r = 0; r < 4; ++r) Lr[r] = __shfl(L, lq * 4 + r, 64);

    #pragma unroll
    for (int n = 0; n < 4; ++n)
        #pragma unroll
        for (int r = 0; r < 4; ++r) {
            int row = q0 + lq * 4 + r;
            float v = acc[n][r] / Lr[r];
            y[((long)(b * T_SEQ) + row) * CDIM + h * HDIM + n * 16 + lr] = f2h(v);
        }
}

extern "C" void kernel_launch(void* const* d_in, const int* in_sizes, int n_in,
                              void* d_out, int out_size, void* d_ws, size_t ws_size,
                              hipStream_t stream) {
    const float* x      = (const float*)d_in[0];
    const float* w_attn = (const float*)d_in[1];
    const float* b_attn = (const float*)d_in[2];
    const float* w_proj = (const float*)d_in[3];
    const float* b_proj = (const float*)d_in[4];
    float* out = (float*)d_out;

    char* ws = (char*)d_ws;
    _Float16* xb  = (_Float16*)(ws);                // 6,291,456
    _Float16* wTa = (_Float16*)(ws + 6291456);      // 3,538,944
    _Float16* wTp = (_Float16*)(ws + 9830400);      // 1,179,648
    _Float16* Qb  = (_Float16*)(ws + 11010048);     // 6,291,456
    _Float16* Kb  = (_Float16*)(ws + 17301504);     // 6,291,456
    _Float16* Vt  = (_Float16*)(ws + 23592960);     // 6,291,456
    _Float16* yb  = (_Float16*)(ws + 29884416);     // 6,291,456

    prologue<<<3072, 256, 0, stream>>>(x, w_attn, w_proj, xb, wTa, wTp);

    gemm_qkv<<<dim3(BT / 128, C3 / 96), 256, 0, stream>>>(xb, wTa, b_attn, Qb, Kb, Vt);

    attn_kernel<<<BH * (T_SEQ / 64), 256, 0, stream>>>(Qb, Kb, Vt, yb);

    gemm_proj<<<dim3(BT / 64, CDIM / 96), 256, 0, stream>>>(yb, wTp, b_proj, out);
}